// Round 2
// baseline (31774.359 us; speedup 1.0000x reference)
//
#include <hip/hip_runtime.h>
#include <hip/hip_cooperative_groups.h>

namespace cg = cooperative_groups;

// Problem constants (match the reference)
constexpr int T_STEPS = 500;
constexpr int BSZ     = 256;   // trials per stimulus
constexpr int NRN     = 512;   // neurons
constexpr int KIN     = 512;   // n_in

// grid = 256 blocks = 16 batch-groups x 16 neuron-groups
// block = 256 threads = 8 batch-pairs x 32 neuron lanes
// Each thread owns 2 batch rows (b0,b1) x 1 neuron column n.
// h1/r1 columns for this block's 32 neurons live in LDS for the whole sim
// (transposed, XOR-swizzled). Spike bits are exchanged via a double-buffered
// bitmask in global scratch + one grid.sync per step.

#define SYN4(acc, xv, hv)                                 \
    acc = fma((double)(xv).x, (double)(hv).x, acc);       \
    acc = fma((double)(xv).y, (double)(hv).y, acc);       \
    acc = fma((double)(xv).z, (double)(hv).z, acc);       \
    acc = fma((double)(xv).w, (double)(hv).w, acc);

#define REC4(acc, msk, sh, rv)                                        \
    acc += (((msk) >> ((sh) + 0)) & 1u) ? (double)(rv).x : 0.0;       \
    acc += (((msk) >> ((sh) + 1)) & 1u) ? (double)(rv).y : 0.0;       \
    acc += (((msk) >> ((sh) + 2)) & 1u) ? (double)(rv).z : 0.0;       \
    acc += (((msk) >> ((sh) + 3)) & 1u) ? (double)(rv).w : 0.0;

__global__ __launch_bounds__(256, 1)
void lif_sim(const float* __restrict__ x,
             const float* __restrict__ h1,
             const float* __restrict__ r1,
             float* __restrict__ out,
             unsigned int* __restrict__ spkbuf)
{
    __shared__ float hL[32 * 512];   // 64 KiB: h1 columns, [n_local][i^swz]
    __shared__ float rL[32 * 512];   // 64 KiB: r1 columns

    const int tid = threadIdx.x;
    const int nl  = tid & 31;        // neuron lane 0..31
    const int bp  = tid >> 5;        // batch pair 0..7
    const int ng  = blockIdx.x & 15; // neuron group
    const int bg  = blockIdx.x >> 4; // batch group
    const int n   = ng * 32 + nl;    // global neuron column
    const int b0  = bg * 16 + bp * 2;
    const int b1  = b0 + 1;

    // --- stage h1 / r1 columns (transposed, swizzled) ---
    for (int idx = tid; idx < 32 * 512; idx += 256) {
        const int nn = idx & 31;
        const int i  = idx >> 5;
        const int d  = nn * 512 + (i ^ ((nn & 7) << 2));
        const int s  = i * NRN + ng * 32 + nn;
        hL[d] = h1[s];
        rL[d] = r1[s];
    }
    __syncthreads();

    const int swb = (nl & 7) << 2;

    // column sum of r1 (f64) for the all-neurons-spiking fast path
    double csum = 0.0;
    for (int i = 0; i < 512; i += 4) {
        const float4 rv = *reinterpret_cast<const float4*>(&rL[nl * 512 + (i ^ swb)]);
        csum += (double)rv.x + (double)rv.y + (double)rv.z + (double)rv.w;
    }

    // zero the spike-bit double buffer (2 x 256 rows x 16 words)
    {
        const int g = blockIdx.x * 256 + tid;
        if (g < 2 * BSZ * 16) spkbuf[g] = 0u;
    }

    cg::grid_group grid = cg::this_grid();
    grid.sync();

    // neuron state (f64, in registers)
    double V0 = 1.0, V1 = 1.0;
    double Is0 = 0.0, Is1 = 0.0;
    double Ir0 = 0.0, Ir1 = 0.0;
    double c0 = 0.0, c1 = 0.0;

    constexpr double DT      = 0.001;
    constexpr double TAU_SYN = 0.01;
    constexpr double TAU_NEU = 0.02;
    const double kS = DT / TAU_SYN;   // 0.1
    const double kN = DT / TAU_NEU;   // 0.05
    const double steady = 0.01 * (double)n;  // I_minimum + I_step * n

    for (int t = 0; t < T_STEPS; ++t) {
        const float* __restrict__ xt = x + (size_t)t * BSZ * KIN;
        const unsigned int* __restrict__ cur = spkbuf + (size_t)(t & 1) * (BSZ * 16);
        unsigned int* __restrict__ nxt       = spkbuf + (size_t)((t + 1) & 1) * (BSZ * 16);

        // did ALL neurons of both rows spike last step?
        int pc = 0;
        #pragma unroll
        for (int k = 0; k < 16; ++k)
            pc += __popc(cur[b0 * 16 + k]) + __popc(cur[b1 * 16 + k]);
        const bool allfull = (pc == 1024);

        double aS0 = 0.0, aS1 = 0.0, aR0 = 0.0, aR1 = 0.0;

        if (allfull) {
            // recurrent term = full column sum (exact same f64 values, reassoc only)
            aR0 = csum;
            aR1 = csum;
            for (int k = 0; k < 16; ++k) {
                #pragma unroll
                for (int j = 0; j < 8; ++j) {
                    const int i = k * 32 + j * 4;
                    const float4 hv = *reinterpret_cast<const float4*>(&hL[nl * 512 + (i ^ swb)]);
                    const float4 xa = *reinterpret_cast<const float4*>(xt + (size_t)b0 * KIN + i);
                    const float4 xb = *reinterpret_cast<const float4*>(xt + (size_t)b1 * KIN + i);
                    SYN4(aS0, xa, hv)
                    SYN4(aS1, xb, hv)
                }
            }
        } else {
            for (int k = 0; k < 16; ++k) {
                const unsigned int wa = cur[b0 * 16 + k];
                const unsigned int wb = cur[b1 * 16 + k];
                #pragma unroll
                for (int j = 0; j < 8; ++j) {
                    const int i = k * 32 + j * 4;
                    const float4 hv = *reinterpret_cast<const float4*>(&hL[nl * 512 + (i ^ swb)]);
                    const float4 rv = *reinterpret_cast<const float4*>(&rL[nl * 512 + (i ^ swb)]);
                    const float4 xa = *reinterpret_cast<const float4*>(xt + (size_t)b0 * KIN + i);
                    const float4 xb = *reinterpret_cast<const float4*>(xt + (size_t)b1 * KIN + i);
                    SYN4(aS0, xa, hv)
                    SYN4(aS1, xb, hv)
                    REC4(aR0, wa, j * 4, rv)
                    REC4(aR1, wb, j * 4, rv)
                }
            }
        }

        // --- neuron update (f64, mirrors reference semantics) ---
        Is0 = Is0 - kS * Is0 + aS0;              // gain_syn = 1
        Is1 = Is1 - kS * Is1 + aS1;
        Ir0 = Ir0 - kS * Ir0 + 0.5 * aR0;        // gain_syn_rec = 0.5
        Ir1 = Ir1 - kS * Ir1 + 0.5 * aR1;

        double Vn0 = V0 - kN * V0 + DT * (Is0 + Ir0 + steady);
        double Vn1 = V1 - kN * V1 + DT * (Is1 + Ir1 + steady);
        Vn0 = fmax(Vn0, 0.0);
        Vn1 = fmax(Vn1, 0.0);

        const bool sp0 = (Vn0 - 1.0) > 0.0;
        const bool sp1 = (Vn1 - 1.0) > 0.0;

        c0 = sp0 ? 2.0 : (c0 - 1.0);             // REFR = 2
        c1 = sp1 ? 2.0 : (c1 - 1.0);
        V0 = sp0 ? 0.0 : ((c0 <= 0.0) ? Vn0 : 0.0);
        V1 = sp1 ? 0.0 : ((c1 <= 0.0) ? Vn1 : 0.0);

        // output spikes
        const size_t ob = (size_t)t * (BSZ * NRN);
        out[ob + (size_t)b0 * NRN + n] = sp0 ? 1.0f : 0.0f;
        out[ob + (size_t)b1 * NRN + n] = sp1 ? 1.0f : 0.0f;

        // publish spike bits: each 64-lane wave holds 2 batch rows x 32 neurons
        const unsigned long long m0 = __ballot(sp0);
        const unsigned long long m1 = __ballot(sp1);
        if (nl == 0) {
            nxt[b0 * 16 + ng] = (unsigned int)((bp & 1) ? (m0 >> 32) : (m0 & 0xffffffffULL));
            nxt[b1 * 16 + ng] = (unsigned int)((bp & 1) ? (m1 >> 32) : (m1 & 0xffffffffULL));
        }
        __threadfence();
        grid.sync();
    }
}

extern "C" void kernel_launch(void* const* d_in, const int* in_sizes, int n_in,
                              void* d_out, int out_size, void* d_ws, size_t ws_size,
                              hipStream_t stream) {
    const float* x  = (const float*)d_in[0];
    const float* h1 = (const float*)d_in[1];
    const float* r1 = (const float*)d_in[2];
    float* out = (float*)d_out;
    unsigned int* spk = (unsigned int*)d_ws;

    void* args[] = { (void*)&x, (void*)&h1, (void*)&r1, (void*)&out, (void*)&spk };
    (void)hipLaunchCooperativeKernel((const void*)lif_sim, dim3(256), dim3(256),
                                     args, 0, stream);
}

// Round 3
// 3097.156 us; speedup vs baseline: 10.2592x; 10.2592x over previous
//
#include <hip/hip_runtime.h>

// LIF sim, decoupled: feed-forward GEMM (parallel) + block-local scan.
// Block b owns batch row b (512 neurons = 512 threads). No grid-wide sync.
constexpr int T_STEPS = 500;
constexpr int BSZ     = 256;
constexpr int NRN     = 512;
constexpr int KIN     = 512;
constexpr int TCH     = 25;   // timesteps per chunk (acc[] in registers)
constexpr int NCH     = 20;   // 20 * 25 = 500

__global__ __launch_bounds__(512, 2)
void lif_sim(const float* __restrict__ x,
             const float* __restrict__ h1,
             const float* __restrict__ r1,
             float* __restrict__ out)
{
    __shared__ float xb[TCH * KIN];               // 50 KB: x rows for this chunk
    __shared__ unsigned long long smask[2][8];    // double-buffered 512-bit spike mask

    const int n  = threadIdx.x;   // neuron 0..511
    const int b  = blockIdx.x;    // batch row
    const int wv = n >> 6;        // wave 0..7
    const int ln = n & 63;        // lane

    if (n < 16) ((unsigned long long*)smask)[n] = 0ULL;

    // csum = sequential f64 sum of r1 column n (== dense recurrent sum for a full mask)
    double csum = 0.0;
    for (int j = 0; j < KIN; ++j)
        csum += (double)r1[(size_t)j * NRN + n];          // coalesced across n

    // neuron state (f64 registers) — identical semantics to the verified kernel
    double V = 1.0, Is = 0.0, Ir = 0.0, cnt = 0.0;
    const double steady = 0.01 * (double)n;
    constexpr double kS = 0.1;     // DT/TAU_SYN
    constexpr double kN = 0.05;    // DT/TAU_NEU
    constexpr double DT = 0.001;

    __syncthreads();

    for (int c = 0; c < NCH; ++c) {
        // ---- stage x chunk: [TCH][KIN] f32, coalesced float4 ----
        for (int idx = n; idx < TCH * KIN / 4; idx += 512) {
            const int t  = idx >> 7;      // / (KIN/4)
            const int i4 = idx & 127;
            const float4 v = *reinterpret_cast<const float4*>(
                x + ((size_t)(c * TCH + t) * BSZ + b) * KIN + i4 * 4);
            *reinterpret_cast<float4*>(&xb[t * KIN + i4 * 4]) = v;
        }
        __syncthreads();

        // ---- GEMM phase: acc[t] = sum_i x[t][i] * h1[i][n], f64, ascending i ----
        double acc[TCH];
        #pragma unroll
        for (int t = 0; t < TCH; ++t) acc[t] = 0.0;

        for (int it = 0; it < KIN; it += 32) {        // runtime i-tile loop
            float hreg[32];
            #pragma unroll
            for (int k = 0; k < 32; ++k)
                hreg[k] = h1[(size_t)(it + k) * NRN + n];   // coalesced, L2-hot
            #pragma unroll
            for (int k4 = 0; k4 < 8; ++k4) {
                #pragma unroll
                for (int t = 0; t < TCH; ++t) {       // 25 independent FMA chains
                    const float4 xv = *reinterpret_cast<const float4*>(
                        &xb[t * KIN + it + k4 * 4]);  // LDS broadcast read
                    acc[t] = fma((double)xv.x, (double)hreg[k4 * 4 + 0], acc[t]);
                    acc[t] = fma((double)xv.y, (double)hreg[k4 * 4 + 1], acc[t]);
                    acc[t] = fma((double)xv.z, (double)hreg[k4 * 4 + 2], acc[t]);
                    acc[t] = fma((double)xv.w, (double)hreg[k4 * 4 + 3], acc[t]);
                }
            }
        }
        __syncthreads();

        // ---- scan phase: 25 sequential steps, block-local spike exchange ----
        #pragma unroll
        for (int t = 0; t < TCH; ++t) {               // unrolled: acc[t] stays in regs
            const int gt = c * TCH + t;
            const int p  = gt & 1;

            unsigned long long mw[8];
            int pc = 0;
            #pragma unroll
            for (int w = 0; w < 8; ++w) { mw[w] = smask[p][w]; pc += __popcll(mw[w]); }

            double aR;
            if (pc == 512) {
                aR = csum;                             // == dense ascending-j sum
            } else if (pc == 0) {
                aR = 0.0;
            } else {
                aR = 0.0;
                #pragma unroll
                for (int w = 0; w < 8; ++w) {
                    unsigned long long m = mw[w];
                    while (m) {                        // ascending j, block-uniform
                        const int j = w * 64 + __builtin_ctzll(m);
                        aR += (double)r1[(size_t)j * NRN + n];   // coalesced
                        m &= m - 1;
                    }
                }
            }

            const double aS = acc[t];
            Is = Is - kS * Is + aS;                    // gain_syn = 1
            Ir = Ir - kS * Ir + 0.5 * aR;              // gain_syn_rec = 0.5
            double Vn = V - kN * V + DT * (Is + Ir + steady);
            Vn = fmax(Vn, 0.0);
            const bool sp = (Vn - 1.0) > 0.0;
            cnt = sp ? 2.0 : (cnt - 1.0);              // REFR = 2
            V = sp ? 0.0 : ((cnt <= 0.0) ? Vn : 0.0);

            out[(size_t)gt * (BSZ * NRN) + (size_t)b * NRN + n] = sp ? 1.0f : 0.0f;

            const unsigned long long bal = __ballot(sp);
            if (ln == 0) smask[p ^ 1][wv] = bal;
            __syncthreads();
        }
    }
}

extern "C" void kernel_launch(void* const* d_in, const int* in_sizes, int n_in,
                              void* d_out, int out_size, void* d_ws, size_t ws_size,
                              hipStream_t stream) {
    const float* x  = (const float*)d_in[0];
    const float* h1 = (const float*)d_in[1];
    const float* r1 = (const float*)d_in[2];
    float* out = (float*)d_out;
    (void)d_ws; (void)ws_size;

    lif_sim<<<dim3(BSZ), dim3(512), 0, stream>>>(x, h1, r1, out);
}